// Round 13
// baseline (103.192 us; speedup 1.0000x reference)
//
#include <hip/hip_runtime.h>
#include <math.h>

#define BB 1024
#define TT 500
#define CC_ 64
#define KK 2000

#define LOG2E 1.44269504088896340736f
#define LN2   0.69314718055994530942f

typedef float f32x4 __attribute__((ext_vector_type(4)));
typedef float f32x2 __attribute__((ext_vector_type(2)));

// ---- fast hardware exp2/log2 (v_exp_f32 / v_log_f32) ----
#if __has_builtin(__builtin_amdgcn_exp2f)
__device__ __forceinline__ float fast_exp2(float x) { return __builtin_amdgcn_exp2f(x); }
#else
__device__ __forceinline__ float fast_exp2(float x) { return exp2f(x); }
#endif
#if __has_builtin(__builtin_amdgcn_logf)
__device__ __forceinline__ float fast_log2(float x) { return __builtin_amdgcn_logf(x); }
#else
__device__ __forceinline__ float fast_log2(float x) { return log2f(x); }
#endif

// max-guarded log2-sum-exp2 (off the hot loop)
__device__ __forceinline__ float lse2_2(float a, float b) {
    float m = fmaxf(a, b);
    float d = fminf(a, b) - m;              // <= 0
    return m + fast_log2(1.0f + fast_exp2(d));
}

// ---- DPP adds (VALU pipe, no LDS) ----
template<int CTRL, int RM, int BM>
__device__ __forceinline__ float dpp_add(float x) {
    int s = __builtin_amdgcn_update_dpp(0, __float_as_int(x), CTRL, RM, BM, true);
    return x + __int_as_float(s);
}
// full 64-lane sum into lane 63 (precompute only)
__device__ __forceinline__ float wave_sum63(float x) {
    x = dpp_add<0x111, 0xf, 0xf>(x);  // row_shr:1
    x = dpp_add<0x112, 0xf, 0xf>(x);  // row_shr:2
    x = dpp_add<0x114, 0xf, 0xf>(x);  // row_shr:4
    x = dpp_add<0x118, 0xf, 0xf>(x);  // row_shr:8
    x = dpp_add<0x142, 0xa, 0xf>(x);  // row_bcast15 (rows 1,3)
    x = dpp_add<0x143, 0xc, 0xf>(x);  // row_bcast31 (rows 2,3)
    return x;
}
// sum over the 16-lane DPP row; result in EVERY lane of the row (rotations)
__device__ __forceinline__ float rowsum16(float x) {
    x = dpp_add<0x121, 0xf, 0xf>(x);  // row_ror:1
    x = dpp_add<0x122, 0xf, 0xf>(x);  // row_ror:2
    x = dpp_add<0x124, 0xf, 0xf>(x);  // row_ror:4
    x = dpp_add<0x128, 0xf, 0xf>(x);  // row_ror:8
    return x;
}

// Precompute per-k tables (log2 units):
//   PA[k]    = {a1[0][0], a1[0][1], a1[1][0], a1[1][1]}         (for finish_py)
//   P3[k][y] = {2^(sel0+q00), 2^(sel0+q10), sel1+q01, sel1+q11} (for bkt_main)
__global__ __launch_bounds__(64) void precompute_P(
    const float* __restrict__ A,
    const float* __restrict__ trans_logits,
    const float* __restrict__ obs_logits,
    float* __restrict__ PA,
    float* __restrict__ P3)
{
    int k = blockIdx.x;
    int c = threadIdx.x;  // 0..63

    float ob[2][2];
#pragma unroll
    for (int s = 0; s < 2; ++s) {
        float o0 = obs_logits[c * 4 + s * 2 + 0] * LOG2E;
        float o1 = obs_logits[c * 4 + s * 2 + 1] * LOG2E;
        float l = lse2_2(o0, o1);
        ob[s][0] = o0 - l;
        ob[s][1] = o1 - l;
    }
    float lt[2][2];
    {
        float t00 = trans_logits[c * 4 + 0] * LOG2E;
        float t01 = trans_logits[c * 4 + 1] * LOG2E;
        float t10 = trans_logits[c * 4 + 2] * LOG2E;
        float t11 = trans_logits[c * 4 + 3] * LOG2E;
        float l0 = lse2_2(t00, t10);  // normalize over s (axis=1), u=0
        float l1 = lse2_2(t01, t11);  // u=1
        lt[0][0] = t00 - l0; lt[0][1] = t01 - l1;
        lt[1][0] = t10 - l0; lt[1][1] = t11 - l1;
    }

    float a = A[k * CC_ + c];
    float v[8];
    v[0] = a * ob[0][0]; v[1] = a * ob[0][1];
    v[2] = a * ob[1][0]; v[3] = a * ob[1][1];
    v[4] = a * lt[0][0]; v[5] = a * lt[0][1];
    v[6] = a * lt[1][0]; v[7] = a * lt[1][1];

#pragma unroll
    for (int i = 0; i < 8; ++i) v[i] = wave_sum63(v[i]);
    if (c == 63) {
        ((float4*)PA)[k] = make_float4(v[0], v[1], v[2], v[3]);
#pragma unroll
        for (int y = 0; y < 2; ++y) {
            float sel0 = v[y];      // a1[0][y]
            float sel1 = v[2 + y];  // a1[1][y]
            ((float4*)P3)[k * 2 + y] = make_float4(
                fast_exp2(sel0 + v[4]),   // E0 = 2^(sel0+q00)
                fast_exp2(sel0 + v[6]),   // E1 = 2^(sel0+q10)
                sel1 + v[5],              // v0 = sel1+q01
                sel1 + v[7]);             // v1 = sel1+q11
        }
    }
}

// Serial forward pass, 4 batches per wave (group g = lane>>4, lane i = lane&15
// holds chains 4i..4i+3). ROUND 13: ONE-level look-ahead link.
//   x01(t+1) = T1(t) - x0(t)*S2(t) + a3'(t)*S3(t)
//   T1(t) = sum u_t*la(t),  u_t = cc_{t+1}(1-cc_t),
//   S2(t) = sum u_t,        S3(t) = sum cc_{t+1}cc_t
// ALL reductions computed FRESH from la(t) each step (no carried x0p/a3p/W
// state — R11/R12's two-level scheme carried error in 3 state vars, gain>1,
// saturated drift 0.14; the R12 anchor reset only x01, hence identical
// failures). One-level error dynamics: common-mode gain S2 < 1 (strict),
// diff-mode ~ S3 << 1 -> stable. Critical cycle is 2-step pipelined:
// a3'(t) -> la(t+1) -> T1(t+1) [tree+4 DPP hops, OFF the d-path] ->
// x01(t+2); the d->exp2->log2 chain of each step runs in parallel with the
// other phase. la(t) itself is updated by the DIRECT formula (unchanged
// from the passing R10). Memory: R10's proven asm skeleton (A/P3 distance
// 6, ky at t+13, 5 ops/step) with vmcnt(24) (guarantees A/P3(t+1) -> cc1).
__global__ __launch_bounds__(64, 1) void bkt_main(
    const int* __restrict__ corr,
    const int* __restrict__ kc,
    const float* __restrict__ A,
    const float* __restrict__ init_logits,
    const float* __restrict__ P3,
    float* __restrict__ out)
{
    int lane = threadIdx.x;
    int g = lane >> 4, i = lane & 15;
    int b = blockIdx.x * 4 + g;
    int bTT  = b * TT;
    int bTT4 = bTT * 4;
    int bTT8 = bTT * 8;
    int i16  = i * 16;

    f32x2 la2[4];
#pragma unroll
    for (int j = 0; j < 4; ++j) {
        float i0 = init_logits[(4 * i + j) * 2 + 0] * LOG2E;
        float i1 = init_logits[(4 * i + j) * 2 + 1] * LOG2E;
        float l = lse2_2(i0, i1);
        la2[j].x = i0 - l;
        la2[j].y = i1 - l;
    }

    int   kq[8], yq[8];     // ky ring: slot (t+13)&7 written at step t
    f32x4 ccq[8], pq[8];    // A/P3 ring: slot (t+6)&7 written at step t

    // ---- memory prologue (R10 verbatim) ----
#pragma unroll
    for (int q = 0; q < 8; ++q) {
        asm volatile("global_load_dword %0, %2, %3\n\t"
                     "global_load_dword %1, %2, %4"
                     : "=&v"(kq[q]), "=&v"(yq[q])
                     : "v"(bTT4 + q * 4), "s"(kc), "s"(corr));
    }
#pragma unroll
    for (int q = 0; q < 8; ++q)
        asm volatile("s_waitcnt vmcnt(0)" : "+v"(kq[q]), "+v"(yq[q]));
    // A/P3 for steps 0..5
#pragma unroll
    for (int q = 0; q < 6; ++q) {
        int va = (kq[q] << 8) + i16;
        int vp = ((kq[q] << 1) + yq[q]) << 4;
        asm volatile("global_load_dwordx4 %0, %1, %2" : "=&v"(ccq[q]) : "v"(va), "s"(A));
        asm volatile("global_load_dwordx4 %0, %1, %2" : "=&v"(pq[q])  : "v"(vp), "s"(P3));
    }
    // ky(8..12) -> slots 0..4
#pragma unroll
    for (int q = 0; q < 5; ++q) {
        asm volatile("global_load_dword %0, %2, %3\n\t"
                     "global_load_dword %1, %2, %4"
                     : "=&v"(kq[q]), "=&v"(yq[q])
                     : "v"(bTT4 + (8 + q) * 4), "s"(kc), "s"(corr));
    }
    // drain once; tie everything outstanding
#pragma unroll
    for (int q = 0; q < 5; ++q)
        asm volatile("s_waitcnt vmcnt(0)" : "+v"(kq[q]), "+v"(yq[q]));
#pragma unroll
    for (int q = 0; q < 6; ++q)
        asm volatile("s_waitcnt vmcnt(0)" : "+v"(ccq[q]), "+v"(pq[q]));

    // ---- compute prologue: seed x01(0) directly from la(0) ----
    f32x2 x01;
    {
        f32x4 c0 = ccq[0];
        f32x2 s = la2[0] * c0.x + la2[1] * c0.y + la2[2] * c0.z + la2[3] * c0.w;
        x01.x = rowsum16(s.x);
        x01.y = rowsum16(s.y);
    }

    // ---- main loop: 63 x 8 = 504 steps; t=500..503 phantoms ----
    for (int tt = 0; tt <= 496; tt += 8) {
#pragma unroll
        for (int j = 0; j < 8; ++j) {
            int t = tt + j;
            // ops 1,2: ky(t+13) into slot (j+5)&7
            int t13 = t + 13; if (t13 > TT - 1) t13 = TT - 1;
            asm volatile("global_load_dword %0, %2, %3\n\t"
                         "global_load_dword %1, %2, %4"
                         : "=&v"(kq[(j + 5) & 7]), "=&v"(yq[(j + 5) & 7])
                         : "v"(bTT4 + t13 * 4), "s"(kc), "s"(corr));
            // ops 3,4: A/P3 for step t+6
            int k6 = kq[(j + 6) & 7], y6 = yq[(j + 6) & 7];
            int va = (k6 << 8) + i16;
            int vp = ((k6 << 1) + y6) << 4;
            asm volatile("global_load_dwordx4 %0, %1, %2"
                         : "=&v"(ccq[(j + 6) & 7]) : "v"(va), "s"(A));
            asm volatile("global_load_dwordx4 %0, %1, %2"
                         : "=&v"(pq[(j + 6) & 7]) : "v"(vp), "s"(P3));
            // wait vmcnt(24): newest 24 = this step's 4 loads + 4 full steps
            // -> everything <= step t-5 complete: A/P3(t+1) (cc1!), pq(t),
            // cc(t), ky(t+7/t+8). Ties = data deps (no hoisting past wait).
            asm volatile("s_waitcnt vmcnt(24)"
                         : "+v"(ccq[j]), "+v"(pq[j]), "+v"(ccq[(j + 1) & 7]),
                           "+v"(kq[(j + 7) & 7]), "+v"(yq[(j + 7) & 7]));

            f32x4 cc  = ccq[j];
            f32x4 pr  = pq[j];
            f32x4 cc1 = ccq[(j + 1) & 7];

            // ---- fresh per-step reductions (start early; consumed at the
            // link at the END of this step => tree+4 hops are off the d-path)
            f32x4 uv = cc1 - cc1 * cc;          // u_t = cc_{t+1}(1-cc_t)
            f32x4 mv = cc * cc1;                // integrand of S3
            f32x2 t1 = la2[0] * uv.x + la2[1] * uv.y
                     + la2[2] * uv.z + la2[3] * uv.w;
            float T1x = rowsum16(t1.x);
            float T1y = rowsum16(t1.y);
            float S2  = rowsum16((uv.x + uv.y) + (uv.z + uv.w));
            float S3  = rowsum16((mv.x + mv.y) + (mv.z + mv.w));

            // ---- serial tail: d(t) -> a3'(t) (no cross-lane ops) ----
            float d   = x01.y - x01.x;
            float a30 = fast_log2(pr.x + fast_exp2(pr.z + d));
            float a31 = fast_log2(pr.y + fast_exp2(pr.w + d));
            f32x2 a3n; a3n.x = a30; a3n.y = a31;
            float x0t = x01.x;

            // store raw (r0,r1)(t); identical across the group's 16 lanes
            if (t < TT) {
                asm volatile("global_store_dwordx2 %1, %0, %2"
                             :: "v"(x01), "v"(bTT8 + t * 8), "s"(out));
            }

            // ---- link: x01(t+1) = T1 - x0*S2 + a3'*S3 (exact identity) ----
            f32x2 T1v; T1v.x = T1x; T1v.y = T1y;
            f32x2 x01n = T1v - x0t * S2;
            x01n = x01n + a3n * S3;

            // ---- la(t+1) by the DIRECT formula (unchanged from R10) ----
            f32x2 gg;
            gg = la2[0] - x0t; la2[0] = gg + (a3n - gg) * cc.x;
            gg = la2[1] - x0t; la2[1] = gg + (a3n - gg) * cc.y;
            gg = la2[2] - x0t; la2[2] = gg + (a3n - gg) * cc.z;
            gg = la2[3] - x0t; la2[3] = gg + (a3n - gg) * cc.w;

            x01 = x01n;
        }
    }
}

// Fully parallel epilogue: stored (r0,r1) -> log-softmax'd output (nat-log).
__global__ __launch_bounds__(256) void finish_py(
    const int* __restrict__ kc,
    const float* __restrict__ PA,
    float* __restrict__ out)
{
    int idx = blockIdx.x * 256 + threadIdx.x;  // idx = b*TT + t
    if (idx >= BB * TT) return;
    int k = kc[idx];
    float2 r  = ((const float2*)out)[idx];
    float4 pa = ((const float4*)PA)[k];
    float lo0 = lse2_2(pa.x + r.x, pa.z + r.y);  // log2 p(y=0) (shifted)
    float lo1 = lse2_2(pa.y + r.x, pa.w + r.y);  // log2 p(y=1) (shifted)
    float lz  = lse2_2(lo0, lo1);
    ((float2*)out)[idx] = make_float2((lo0 - lz) * LN2, (lo1 - lz) * LN2);
}

extern "C" void kernel_launch(void* const* d_in, const int* in_sizes, int n_in,
                              void* d_out, int out_size, void* d_ws, size_t ws_size,
                              hipStream_t stream) {
    const int* corr    = (const int*)d_in[0];
    const int* kc      = (const int*)d_in[1];
    const float* A     = (const float*)d_in[2];
    const float* trans = (const float*)d_in[3];
    const float* obs   = (const float*)d_in[4];
    const float* init  = (const float*)d_in[5];
    float* out = (float*)d_out;

    float* PA = (float*)d_ws;          // K*4 floats = 32 KB
    float* P3 = PA + KK * 4;           // K*2*4 floats = 64 KB (total 96 KB)

    precompute_P<<<KK, 64, 0, stream>>>(A, trans, obs, PA, P3);
    bkt_main<<<BB / 4, 64, 0, stream>>>(corr, kc, A, init, P3, out);
    finish_py<<<(BB * TT + 255) / 256, 256, 0, stream>>>(kc, PA, out);
}